// Round 6
// baseline (168.523 us; speedup 1.0000x reference)
//
#include <hip/hip_runtime.h>
#include <stdint.h>

typedef unsigned long long u64;
typedef unsigned int u32;

#define NBINS 512
#define CAP 512
#define LOG_CUT (-64.0f)
#define LOG_SCALE 20.0f
#define NT 512
#define NWAVE (NT / 64)
#define MAXW 256            // bitmap words: M/64 <= 256 (M = 16384)

// One fused kernel, one workgroup per batch row.
// Phase S: batched-load streaming -> usage (bit-exact f32) -> LDS + global.
// Phase H (x W heads): log-histogram -> suffix scan -> ballot compact (+bitmap) ->
//   O(K^2) pairwise rank -> DENSE alloc row write (bitmap + popcount prefix).
// LDS: uS 64KB dyn + ~13.3KB static => 2 blocks/CU.
template <int TW, int TR>
__global__ __launch_bounds__(NT, 4)
void fused_kernel(const float* __restrict__ ww,    // [B,W,M]
                  const float* __restrict__ fg,    // [B,R]
                  const float* __restrict__ rw,    // [B,R,M]
                  const float* __restrict__ prev,  // [B,M]
                  const float* __restrict__ wgt,   // [B,W]
                  float* __restrict__ out_usage,   // [B,M]
                  float* __restrict__ out_alloc,   // [B,W,M]
                  int B, int W, int R, int M)
{
    __shared__ u64   keyS[CAP];
    __shared__ float logS[CAP];
    __shared__ float valS[CAP];
    __shared__ u32   hC[NBINS];
    __shared__ u64   bmS[MAXW];     // candidate bitmap
    __shared__ u32   boS[MAXW];     // exclusive popcount prefix per 64-word
    __shared__ u32   tc[NWAVE];
    __shared__ float twv[NWAVE];
    __shared__ int   misc[4];       // [0]=count, [1]=max xs, [2]=min xc
    extern __shared__ float uS[];   // M floats

    const int Wl = TW > 0 ? TW : W;
    const int Rl = TR > 0 ? TR : R;
    const int b = blockIdx.x;
    const int t = threadIdx.x;
    const int lane = t & 63;
    const int wid = t >> 6;
    const int MW = M >> 6;

    const float C1 = (float)(1.0 - 1e-6);
    const float CE = 1e-6f;

    // ---------------- Phase S: read-dominated streaming ----------------
    // usage = (prev + (1-prev)*(1-prod_w(1-ww))) * prod_r(1-fg*rw), ref f32 op order
    {
        const size_t rowOff = (size_t)b * M;
        const float* wp0 = ww + (size_t)b * Wl * M;
        const float* rp0 = rw + (size_t)b * Rl * M;
        float frs[TR > 0 ? TR : 8];
        #pragma unroll
        for (int r = 0; r < Rl; ++r) frs[r] = fg[(size_t)b * Rl + r];

        for (int m = t * 4; m < M; m += NT * 4) {
            // batch all 13 loads first (load clustering -> deep MLP)
            const float4 pv = *(const float4*)(prev + rowOff + m);
            float4 wv[TW > 0 ? TW : 4];
            float4 rv[TR > 0 ? TR : 8];
            #pragma unroll
            for (int w = 0; w < Wl; ++w)
                wv[w] = *(const float4*)(wp0 + (size_t)w * M + m);
            #pragma unroll
            for (int r = 0; r < Rl; ++r)
                rv[r] = *(const float4*)(rp0 + (size_t)r * M + m);

            float pr0 = 1.f, pr1 = 1.f, pr2 = 1.f, pr3 = 1.f;
            #pragma unroll
            for (int w = 0; w < Wl; ++w) {
                pr0 *= (1.0f - wv[w].x); pr1 *= (1.0f - wv[w].y);
                pr2 *= (1.0f - wv[w].z); pr3 *= (1.0f - wv[w].w);
            }
            float u0 = pv.x + (1.0f - pv.x) * (1.0f - pr0);
            float u1 = pv.y + (1.0f - pv.y) * (1.0f - pr1);
            float u2 = pv.z + (1.0f - pv.z) * (1.0f - pr2);
            float u3 = pv.w + (1.0f - pv.w) * (1.0f - pr3);
            float f0 = 1.f, f1 = 1.f, f2 = 1.f, f3 = 1.f;
            #pragma unroll
            for (int r = 0; r < Rl; ++r) {
                const float fr = frs[r];
                f0 *= (1.0f - fr * rv[r].x); f1 *= (1.0f - fr * rv[r].y);
                f2 *= (1.0f - fr * rv[r].z); f3 *= (1.0f - fr * rv[r].w);
            }
            float4 uo;
            uo.x = u0 * f0; uo.y = u1 * f1; uo.z = u2 * f2; uo.w = u3 * f3;
            *(float4*)(uS + m) = uo;
            *(float4*)(out_usage + rowOff + m) = uo;
        }
    }

    // ---------------- Phase H: per write head ----------------
    for (int i = 0; i < Wl; ++i) {
        const float wgi = wgt[(size_t)b * Wl + i];
        float* orow = out_alloc + ((size_t)b * Wl + i) * M;

        hC[t] = 0u;
        for (int x = t; x < MW; x += NT) bmS[x] = 0ull;
        if (t == 0) { misc[0] = 0; misc[1] = -1; misc[2] = NBINS; }
        __syncthreads();   // orders phase-S LDS writes / prior head updates too

        // count-only log-domain histogram: bkt = floor(-log2(ue)*20)
        for (int x = t * 4; x < M; x += NT * 4) {
            const float4 uu = *(const float4*)(uS + x);
            const float ua[4] = {uu.x, uu.y, uu.z, uu.w};
            #pragma unroll
            for (int j = 0; j < 4; ++j) {
                const float ue = CE + C1 * ua[j];
                const float lg = __log2f(ue);
                int bkt = (int)(-lg * LOG_SCALE);
                bkt = bkt < 0 ? 0 : (bkt > NBINS - 1 ? NBINS - 1 : bkt);
                atomicAdd(&hC[bkt], 1u);
            }
        }
        __syncthreads();

        // parallel suffix scan over buckets (thread t owns x = NBINS-1-t):
        // Sc = suffix count; Sw = conservative log bound (bkt y => log2(ue) <= -y/20)
        {
            const int x = NBINS - 1 - t;
            const u32 c = hC[x];
            u32 sc = c;
            float sw = -(float)x * (1.0f / LOG_SCALE) * (float)c;
            #pragma unroll
            for (int off = 1; off < 64; off <<= 1) {
                const u32  oc = __shfl_up(sc, off);
                const float ow = __shfl_up(sw, off);
                if (lane >= off) { sc += oc; sw += ow; }
            }
            if (lane == 63) { tc[wid] = sc; twv[wid] = sw; }
            __syncthreads();
            u32 ac = 0; float aw = 0.f;
            for (int q = 0; q < wid; ++q) { ac += tc[q]; aw += twv[q]; }
            sc += ac; sw += aw;
            if (sw <= LOG_CUT) atomicMax(&misc[1], x);   // enough log-mass
            if (sc <= (u32)CAP) atomicMin(&misc[2], x);  // within count cap
        }
        __syncthreads();
        const int xs = misc[1];
        const int xc = misc[2];
        const int cut = (xs > xc) ? xs : xc;

        // compact candidates (bkt >= cut): keyS + bitmap, wave-aggregated counter
        // key = (~bits(1-ue) << 14) | idx: asc == nonusage desc, low-idx tiebreak
        for (int x = t; x < M; x += NT) {
            const float u = uS[x];
            const float ue = CE + C1 * u;
            const float lg = __log2f(ue);
            int bkt = (int)(-lg * LOG_SCALE);
            bkt = bkt < 0 ? 0 : (bkt > NBINS - 1 ? NBINS - 1 : bkt);
            const bool pred = (bkt >= cut) && (cut < NBINS);
            const u64 mask = __ballot(pred);
            const int cnt = __popcll(mask);
            if (cnt) {
                int base = 0;
                if (lane == 0) base = atomicAdd(&misc[0], cnt);
                base = __shfl(base, 0);
                if (pred) {
                    const int pos = base + __popcll(mask & ((1ull << lane) - 1));
                    if (pos < CAP) {    // never triggers: count<=CAP by construction
                        const float nn = 1.0f - ue;
                        keyS[pos] = (((u64)(~__float_as_uint(nn))) << 14) | (u64)(u32)x;
                        logS[pos] = lg;
                        atomicOr(&bmS[x >> 6], 1ull << (x & 63));
                    }
                }
            }
        }
        __syncthreads();
        int K = misc[0]; if (K > CAP) K = CAP;

        // exclusive popcount prefix over bitmap words (MW <= 256 -> waves 0..3)
        u32 myinc = 0, mycnt = 0;
        if (t < MW) {
            mycnt = (u32)__popcll(bmS[t]);
            myinc = mycnt;
            #pragma unroll
            for (int off = 1; off < 64; off <<= 1) {
                const u32 o = __shfl_up(myinc, off);
                if (lane >= off) myinc += o;
            }
            if (lane == 63) tc[wid] = myinc;
        }
        __syncthreads();
        if (t < MW) {
            u32 add = 0;
            for (int q = 0; q < wid; ++q) add += tc[q];
            boS[t] = myinc + add - mycnt;    // exclusive prefix
        }
        __syncthreads();

        // pairwise rank: S_t = sum log2(ue_k) over strictly-smaller keys;
        // alloc = nonusage * exp2(S); deposit at x-rank for the dense sweep
        if (t < K) {
            const u64 mykey = keyS[t];
            float S = 0.0f;
            #pragma unroll 4
            for (int k = 0; k < K; ++k) {
                const u64 kk = keyS[k];      // LDS broadcast
                const float lg = logS[k];
                if (kk < mykey) S += lg;
            }
            const float nn = __uint_as_float(~((u32)(mykey >> 14)));
            const int idx = (int)(mykey & 0x3FFFull);
            const float al = nn * __builtin_exp2f(S);
            const u64 wbits = bmS[idx >> 6];
            const int xr = (int)boS[idx >> 6]
                         + (int)__popcll(wbits & ((1ull << (idx & 63)) - 1));
            valS[xr] = al;
            if (al != 0.0f) {
                const float u0v = uS[idx];
                uS[idx] = u0v + ((1.0f - u0v) * wgi) * al;
            }
        }
        __syncthreads();

        // dense alloc row write: big contiguous bursts, zeros + candidate values
        for (int x4 = t * 4; x4 < M; x4 += NT * 4) {
            float4 o;
            float* op = (float*)&o;
            #pragma unroll
            for (int j = 0; j < 4; ++j) {
                const int x = x4 + j;
                const u64 wbits = bmS[x >> 6];
                float v = 0.0f;
                if ((wbits >> (x & 63)) & 1ull) {
                    const int xr = (int)boS[x >> 6]
                                 + (int)__popcll(wbits & ((1ull << (x & 63)) - 1));
                    v = valS[xr];
                }
                op[j] = v;
            }
            *(float4*)(orow + x4) = o;
        }
        __syncthreads();
    }
}

extern "C" void kernel_launch(void* const* d_in, const int* in_sizes, int n_in,
                              void* d_out, int out_size, void* d_ws, size_t ws_size,
                              hipStream_t stream) {
    const float* ww   = (const float*)d_in[0];
    const float* fg   = (const float*)d_in[1];
    const float* rw   = (const float*)d_in[2];
    const float* prev = (const float*)d_in[3];
    const float* wgt  = (const float*)d_in[4];
    const int BWM = in_sizes[0];
    const int BR  = in_sizes[1];
    const int BM  = in_sizes[3];
    const int BW  = in_sizes[4];
    const int M = BWM / BW;
    const int B = BM / M;
    const int W = BW / B;
    const int R = BR / B;

    float* out_usage = (float*)d_out;
    float* out_alloc = out_usage + (size_t)BM;

    const size_t smem = (size_t)M * sizeof(float);   // dynamic: uS only
    if (W == 4 && R == 8) {
        hipLaunchKernelGGL((fused_kernel<4, 8>), dim3(B), dim3(NT), smem, stream,
                           ww, fg, rw, prev, wgt, out_usage, out_alloc, B, W, R, M);
    } else {
        hipLaunchKernelGGL((fused_kernel<0, 0>), dim3(B), dim3(NT), smem, stream,
                           ww, fg, rw, prev, wgt, out_usage, out_alloc, B, W, R, M);
    }
}